// Round 7
// baseline (387.288 us; speedup 1.0000x reference)
//
#include <hip/hip_runtime.h>
#include <math.h>

// Problem constants (from reference): B=4, N=50000, E=800000, D=64
#define NB 4
#define NN 50000
#define NE 800000
#define ND 64
#define ROWB (NB * ND)            // 256 bf16 per node row in (N,B,D)
#define RTOT (NB * NN)            // 200000 rows
#define NBLK ((NN + 255) / 256)   // 196 scan blocks
#define XS_STRIDE 34              // dwords per LDS X row: 32 k-pairs + 2 pad (8B-aligned)

static const long TOT = (long)NB * NN * ND; // 12,800,000 elements

typedef unsigned int uint_t;

// f32 -> bf16 (round-to-nearest-even)
__device__ __forceinline__ unsigned short f2b(float f) {
    unsigned x = __float_as_uint(f);
    unsigned r = (x + 0x7fffu + ((x >> 16) & 1u)) >> 16;
    return (unsigned short)r;
}
__device__ __forceinline__ float b2f(unsigned short u) {
    return __uint_as_float(((unsigned)u) << 16);
}
__device__ __forceinline__ float4 b2f4(ushort4 u) {
    float4 f;
    f.x = b2f(u.x); f.y = b2f(u.y); f.z = b2f(u.z); f.w = b2f(u.w);
    return f;
}

// ---- count in-degree (targets): cnt[col[e]] += 1 ---------------------------
__global__ __launch_bounds__(256) void count_kernel(const int* __restrict__ col,
                                                    int* __restrict__ cnt) {
    int e = blockIdx.x * blockDim.x + threadIdx.x;
    if (e < NE) atomicAdd(&cnt[col[e]], 1);
}

// ---- dis[n] = rsqrt(cnt[n] + 1)  (+1 = self-loop) --------------------------
__global__ __launch_bounds__(256) void dis_kernel(const int* __restrict__ cnt,
                                                  float* __restrict__ dis) {
    int n = blockIdx.x * blockDim.x + threadIdx.x;
    if (n < NN) dis[n] = rsqrtf((float)cnt[n] + 1.0f);
}

// ---- scan stage 1: per-256-chunk sums --------------------------------------
__global__ __launch_bounds__(256) void blocksum_kernel(const int* __restrict__ cnt,
                                                       int* __restrict__ bsum) {
    int i = blockIdx.x * 256 + threadIdx.x;
    int v = (i < NN) ? cnt[i] : 0;
#pragma unroll
    for (int off = 32; off; off >>= 1) v += __shfl_down(v, off);
    __shared__ int s[4];
    if ((threadIdx.x & 63) == 0) s[threadIdx.x >> 6] = v;
    __syncthreads();
    if (threadIdx.x == 0) bsum[blockIdx.x] = s[0] + s[1] + s[2] + s[3];
}

// ---- scan stage 2: exclusive scan of NBLK partials (1 block) ---------------
__global__ __launch_bounds__(256) void scanb_kernel(const int* __restrict__ bsum,
                                                    int* __restrict__ boff,
                                                    int* __restrict__ ptr) {
    __shared__ int s[256];
    int t = threadIdx.x;
    int v = (t < NBLK) ? bsum[t] : 0;
    s[t] = v;
    __syncthreads();
    for (int off = 1; off < 256; off <<= 1) {
        int u = (t >= off) ? s[t - off] : 0;
        __syncthreads();
        s[t] += u;
        __syncthreads();
    }
    boff[t] = s[t] - v; // exclusive
    if (t == 255) ptr[NN] = s[255]; // == NE
}

// ---- scan stage 3: emit ptr / fill -----------------------------------------
__global__ __launch_bounds__(256) void emit_kernel(const int* __restrict__ cnt,
                                                   const int* __restrict__ boff,
                                                   int* __restrict__ ptr,
                                                   int* __restrict__ fill) {
    __shared__ int s[256];
    int t = threadIdx.x;
    int i = blockIdx.x * 256 + t;
    int v = (i < NN) ? cnt[i] : 0;
    s[t] = v;
    __syncthreads();
    for (int off = 1; off < 256; off <<= 1) {
        int u = (t >= off) ? s[t - off] : 0;
        __syncthreads();
        s[t] += u;
        __syncthreads();
    }
    if (i < NN) {
        int ex = boff[blockIdx.x] + s[t] - v;
        ptr[i] = ex;
        fill[i] = ex;
    }
}

// ---- CSR fill: bucket edge sources by target (norm factored out) -----------
__global__ __launch_bounds__(256) void fill_kernel(const int* __restrict__ row,
                                                   const int* __restrict__ col,
                                                   int* __restrict__ fill,
                                                   int* __restrict__ srow) {
    int e = blockIdx.x * blockDim.x + threadIdx.x;
    if (e >= NE) return;
    int r = row[e], c = col[e];
    int p = atomicAdd(&fill[c], 1);
    srow[p] = r;
}

// ---- GEMM v5: xwb[n,b,:] = dis[n] * (x[b,n,:] @ W)  (bf16 out, (N,B,D)) ----
// 128-row tile, 256 threads, microtile 8 rows (r = tg + 16*i) x 4 cols.
// X staged as bf16 pairs in LDS (b64 reads, conflict-free), W f32 in LDS.
template <bool INF32>
__global__ __launch_bounds__(256) void gemm_kernel(const void* __restrict__ xin,
                                                   const float* __restrict__ W,
                                                   const float* __restrict__ dis,
                                                   unsigned short* __restrict__ xwb) {
    __shared__ unsigned XsU[128 * XS_STRIDE]; // 17.4 KB
    __shared__ float Ws[4096];                // 16 KB
    const int tid = threadIdx.x;
    const int row0 = blockIdx.x * 128;

    for (int i = tid; i < 4096; i += 256) Ws[i] = W[i];

    if constexpr (INF32) {
        const float* x = (const float*)xin;
#pragma unroll
        for (int j = 0; j < 8; ++j) {
            int c = tid + j * 256;          // 2048 float4-chunks
            int lr = c >> 4;
            int k0 = (c & 15) * 4;
            int R = row0 + lr;
            float4 xv = (R < RTOT) ? *(const float4*)(x + (long)R * ND + k0)
                                   : make_float4(0.f, 0.f, 0.f, 0.f);
            XsU[lr * XS_STRIDE + (k0 >> 1) + 0] =
                (uint_t)f2b(xv.x) | ((uint_t)f2b(xv.y) << 16);
            XsU[lr * XS_STRIDE + (k0 >> 1) + 1] =
                (uint_t)f2b(xv.z) | ((uint_t)f2b(xv.w) << 16);
        }
    } else {
        const uint_t* x = (const uint_t*)xin; // bf16 pairs, 32 dwords/row
#pragma unroll
        for (int j = 0; j < 4; ++j) {
            int cc = tid + j * 256;         // 1024 uint4-chunks
            int lr = cc >> 3;
            int kd = (cc & 7) * 4;
            int R = row0 + lr;
            uint4 u = (R < RTOT) ? *(const uint4*)(x + (long)R * 32 + kd)
                                 : make_uint4(0u, 0u, 0u, 0u);
            XsU[lr * XS_STRIDE + kd + 0] = u.x;
            XsU[lr * XS_STRIDE + kd + 1] = u.y;
            XsU[lr * XS_STRIDE + kd + 2] = u.z;
            XsU[lr * XS_STRIDE + kd + 3] = u.w;
        }
    }
    __syncthreads();

    const int tc = tid & 15, tg = tid >> 4;
    const int c0 = tc * 4;
    float acc[8][4];
#pragma unroll
    for (int i = 0; i < 8; ++i)
#pragma unroll
        for (int j = 0; j < 4; ++j) acc[i][j] = 0.0f;

#pragma unroll 4
    for (int kk = 0; kk < 16; ++kk) { // 4 k-values per iter
        float4 w0 = *(const float4*)&Ws[(4 * kk + 0) * 64 + c0];
        float4 w1 = *(const float4*)&Ws[(4 * kk + 1) * 64 + c0];
        float4 w2 = *(const float4*)&Ws[(4 * kk + 2) * 64 + c0];
        float4 w3 = *(const float4*)&Ws[(4 * kk + 3) * 64 + c0];
#pragma unroll
        for (int i = 0; i < 8; ++i) {
            uint2 u = *(const uint2*)&XsU[(tg + 16 * i) * XS_STRIDE + 2 * kk];
            float xa = __uint_as_float(u.x << 16);
            float xb = __uint_as_float(u.x & 0xffff0000u);
            float xc = __uint_as_float(u.y << 16);
            float xd = __uint_as_float(u.y & 0xffff0000u);
            acc[i][0] = fmaf(xa, w0.x, acc[i][0]); acc[i][1] = fmaf(xa, w0.y, acc[i][1]);
            acc[i][2] = fmaf(xa, w0.z, acc[i][2]); acc[i][3] = fmaf(xa, w0.w, acc[i][3]);
            acc[i][0] = fmaf(xb, w1.x, acc[i][0]); acc[i][1] = fmaf(xb, w1.y, acc[i][1]);
            acc[i][2] = fmaf(xb, w1.z, acc[i][2]); acc[i][3] = fmaf(xb, w1.w, acc[i][3]);
            acc[i][0] = fmaf(xc, w2.x, acc[i][0]); acc[i][1] = fmaf(xc, w2.y, acc[i][1]);
            acc[i][2] = fmaf(xc, w2.z, acc[i][2]); acc[i][3] = fmaf(xc, w2.w, acc[i][3]);
            acc[i][0] = fmaf(xd, w3.x, acc[i][0]); acc[i][1] = fmaf(xd, w3.y, acc[i][1]);
            acc[i][2] = fmaf(xd, w3.z, acc[i][2]); acc[i][3] = fmaf(xd, w3.w, acc[i][3]);
        }
    }

#pragma unroll
    for (int i = 0; i < 8; ++i) {
        int R = row0 + tg + 16 * i;
        if (R < RTOT) {
            int b = R / NN;
            int n = R - b * NN;
            float sc = dis[n];
            ushort4 p;
            p.x = f2b(acc[i][0] * sc); p.y = f2b(acc[i][1] * sc);
            p.z = f2b(acc[i][2] * sc); p.w = f2b(acc[i][3] * sc);
            *(ushort4*)(xwb + ((long)n * NB + b) * ND + c0) = p;
        }
    }
}

// ---- fused gather: out = tanh(dis[c]*(sum srcs + self) + bias) -------------
// One wave per target node; pure adds (norm factored out).
template <bool OUTF32>
__global__ __launch_bounds__(256) void gather_kernel(const int* __restrict__ ptr,
                                                     const int* __restrict__ srow,
                                                     const float* __restrict__ dis,
                                                     const unsigned short* __restrict__ xwb,
                                                     const float* __restrict__ bias,
                                                     void* __restrict__ outv) {
    int node = __builtin_amdgcn_readfirstlane(blockIdx.x * 4 + (threadIdx.x >> 6));
    const int lane = threadIdx.x & 63;
    const int b = lane >> 4;
    const int d0 = (lane & 15) * 4;

    // self-loop summand: xwb[node] (already dis[node]-scaled)
    float4 acc = b2f4(*(const ushort4*)(xwb + (long)node * ROWB + lane * 4));

    int e = ptr[node];
    const int eend = ptr[node + 1];
    for (; e + 7 < eend; e += 8) {
        int s0 = srow[e + 0], s1 = srow[e + 1], s2 = srow[e + 2], s3 = srow[e + 3];
        int s4 = srow[e + 4], s5 = srow[e + 5], s6 = srow[e + 6], s7 = srow[e + 7];
        float4 v0 = b2f4(*(const ushort4*)(xwb + (long)s0 * ROWB + lane * 4));
        float4 v1 = b2f4(*(const ushort4*)(xwb + (long)s1 * ROWB + lane * 4));
        float4 v2 = b2f4(*(const ushort4*)(xwb + (long)s2 * ROWB + lane * 4));
        float4 v3 = b2f4(*(const ushort4*)(xwb + (long)s3 * ROWB + lane * 4));
        float4 v4 = b2f4(*(const ushort4*)(xwb + (long)s4 * ROWB + lane * 4));
        float4 v5 = b2f4(*(const ushort4*)(xwb + (long)s5 * ROWB + lane * 4));
        float4 v6 = b2f4(*(const ushort4*)(xwb + (long)s6 * ROWB + lane * 4));
        float4 v7 = b2f4(*(const ushort4*)(xwb + (long)s7 * ROWB + lane * 4));
        acc.x += v0.x + v1.x; acc.y += v0.y + v1.y; acc.z += v0.z + v1.z; acc.w += v0.w + v1.w;
        acc.x += v2.x + v3.x; acc.y += v2.y + v3.y; acc.z += v2.z + v3.z; acc.w += v2.w + v3.w;
        acc.x += v4.x + v5.x; acc.y += v4.y + v5.y; acc.z += v4.z + v5.z; acc.w += v4.w + v5.w;
        acc.x += v6.x + v7.x; acc.y += v6.y + v7.y; acc.z += v6.z + v7.z; acc.w += v6.w + v7.w;
    }
    for (; e < eend; ++e) {
        int s = srow[e];
        float4 v = b2f4(*(const ushort4*)(xwb + (long)s * ROWB + lane * 4));
        acc.x += v.x; acc.y += v.y; acc.z += v.z; acc.w += v.w;
    }

    float dn = dis[node];
    float4 bv = *(const float4*)(bias + d0);
    acc.x = tanhf(fmaf(acc.x, dn, bv.x));
    acc.y = tanhf(fmaf(acc.y, dn, bv.y));
    acc.z = tanhf(fmaf(acc.z, dn, bv.z));
    acc.w = tanhf(fmaf(acc.w, dn, bv.w));

    const long oidx = ((long)b * NN + node) * ND + d0; // (B,N,D)
    if constexpr (OUTF32) {
        *(float4*)((float*)outv + oidx) = acc;
    } else {
        ushort4 p;
        p.x = f2b(acc.x); p.y = f2b(acc.y); p.z = f2b(acc.z); p.w = f2b(acc.w);
        *(ushort4*)((unsigned short*)outv + oidx) = p;
    }
}

extern "C" void kernel_launch(void* const* d_in, const int* in_sizes, int n_in,
                              void* d_out, int out_size, void* d_ws, size_t ws_size,
                              hipStream_t stream) {
    // inputs: 0=t, 1=h, 2=edge_index, 3=W1, 4=b1, 5=W2, 6=b2
    const float* h  = (const float*)d_in[1];
    const int*   ei = (const int*)d_in[2];
    const float* W1 = (const float*)d_in[3];
    const float* b1 = (const float*)d_in[4];
    const float* W2 = (const float*)d_in[5];
    const float* b2 = (const float*)d_in[6];
    float* out = (float*)d_out;

    const int* rowp = ei;        // edge_index[0] = sources
    const int* colp = ei + NE;   // edge_index[1] = targets

    // workspace layout
    unsigned short* xwb = (unsigned short*)d_ws;       // TOT bf16 (N,B,D)
    unsigned short* mid = xwb + TOT;                   // TOT bf16 (B,N,D) layer-1 out
    float* dis   = (float*)(mid + TOT);                // NN
    int*   cnt   = (int*)(dis + NN);                   // NN
    int*   ptr   = cnt + NN;                           // NN+1
    int*   fill  = ptr + NN + 1;                       // NN
    int*   srow  = fill + NN;                          // NE
    int*   bsum  = srow + NE;                          // 256
    int*   boff  = bsum + 256;                         // 256

    const int THREADS = 256;
    const int gridE = (NE + THREADS - 1) / THREADS;
    const int gridN = (NN + THREADS - 1) / THREADS;
    const int gridGemm   = (RTOT + 127) / 128;  // 1563
    const int gridGather = NN / 4;              // 12500

    // ---- normalization + CSR build ----
    hipMemsetAsync(cnt, 0, NN * sizeof(int), stream);
    count_kernel<<<gridE, THREADS, 0, stream>>>(colp, cnt);
    dis_kernel<<<gridN, THREADS, 0, stream>>>(cnt, dis);
    blocksum_kernel<<<NBLK, THREADS, 0, stream>>>(cnt, bsum);
    scanb_kernel<<<1, THREADS, 0, stream>>>(bsum, boff, ptr);
    emit_kernel<<<NBLK, THREADS, 0, stream>>>(cnt, boff, ptr, fill);
    fill_kernel<<<gridE, THREADS, 0, stream>>>(rowp, colp, fill, srow);

    // ---- layer 1: h (f32) -> mid (bf16) ----
    gemm_kernel<true><<<gridGemm, THREADS, 0, stream>>>(h, W1, dis, xwb);
    gather_kernel<false><<<gridGather, THREADS, 0, stream>>>(ptr, srow, dis, xwb, b1, mid);

    // ---- layer 2: mid (bf16) -> out (f32) ----
    gemm_kernel<false><<<gridGemm, THREADS, 0, stream>>>(mid, W2, dis, xwb);
    gather_kernel<true><<<gridGather, THREADS, 0, stream>>>(ptr, srow, dis, xwb, b2, out);
}